// Round 7
// baseline (74.165 us; speedup 1.0000x reference)
//
#include <hip/hip_runtime.h>
#include <hip/hip_bf16.h>

#define KAN_GRID 30
#define KAN_HID  16

#define PK   2500    // chunks
#define PL   40      // steps per chunk (PK*PL == T == 100000)
#define SNPT 10      // scan elements per thread (256*10 >= PK)
#define CBLK ((PK + 255) / 256)   // 10 parareal blocks

// ---------------- step macros (round-1 validated arithmetic) ---------------
#define STEP_O(BDT, DST)                            \
    {                                               \
        float x  = S * I;                           \
        float q  = fmaf(-gdt, I, I);                \
        float Sn = fmaf(-(BDT), x, S);              \
        float In = fmaf((BDT), x, q);               \
        Sn = fminf(fmaxf(Sn, 0.0f), 1.0f);          \
        In = fminf(fmaxf(In, 0.0f), 1.0f);          \
        S = Sn; I = In; (DST) = In;                 \
    }

#define STEP_J(BDT)                                          \
    {                                                        \
        float x  = S * I;                                    \
        float u  = (BDT) * I;                                \
        float v  = (BDT) * S;                                \
        float q  = fmaf(-gdt, I, I);                         \
        float Sn = fmaf(-(BDT), x, S);                       \
        float In = fmaf((BDT), x, q);                        \
        Sn = fminf(fmaxf(Sn, 0.0f), 1.0f);                   \
        In = fminf(fmaxf(In, 0.0f), 1.0f);                   \
        float w  = g1 + v;                                   \
        float a2 = fmaf(-v, jc, fmaf(-u, ja, ja));           \
        float b2 = fmaf(-v, jd, fmaf(-u, jb, jb));           \
        float c2 = fmaf(w, jc, u * ja);                      \
        float d2 = fmaf(w, jd, u * jb);                      \
        S = Sn; I = In; ja = a2; jb = b2; jc = c2; jd = d2;  \
    }

#define SOFTPLUS(X) (fmaxf((X), 0.0f) + log1pf(__expf(-fabsf(X))))

// affine map (a,b,c,d | s,i): x -> [[a,b],[c,d]] x + (s,i). compose = L after E.
#define COMPOSE(ra,rb,rc,rd,rs,ri, La,Lb,Lc,Ld,Ls,Li, Ea,Eb,Ec,Ed,Es,Ei)   \
    {                                                                      \
        ra = fmaf(La, Ea, Lb * Ec);                                        \
        rb = fmaf(La, Eb, Lb * Ed);                                        \
        rc = fmaf(Lc, Ea, Ld * Ec);                                        \
        rd = fmaf(Lc, Eb, Ld * Ed);                                        \
        rs = fmaf(La, Es, fmaf(Lb, Ei, Ls));                               \
        ri = fmaf(Lc, Es, fmaf(Ld, Ei, Li));                               \
    }

// ---------------- device helpers -------------------------------------------
// betas body: computes beta(t[n])*dt. Weights already staged in LDS.
__device__ __forceinline__ float kan_beta_eval(
    float tv, const float* s_sw1, const float* s_sw2,
    const float* s_bw1, const float* s_bw2, float dt)
{
    float h[KAN_HID];
#pragma unroll
    for (int j = 0; j < KAN_HID; ++j) h[j] = tv * s_bw1[j];

#pragma unroll
    for (int g = 0; g < KAN_GRID; ++g) {
        float d = tv - (float)g * (1.0f / 29.0f);
        float e = __expf(-20.0f * d * d);
#pragma unroll
        for (int j = 0; j < KAN_HID; ++j)
            h[j] = fmaf(e, s_sw1[g * KAN_HID + j], h[j]);
    }

    float out = 0.0f;
#pragma unroll
    for (int j = 0; j < KAN_HID; ++j) out = fmaf(h[j], s_bw2[j], out);

#pragma unroll
    for (int j = 0; j < KAN_HID; ++j) {
        float hv = h[j];
#pragma unroll
        for (int g = 0; g < KAN_GRID; ++g) {
            float d = hv - (float)g * (1.0f / 29.0f);
            out = fmaf(__expf(-20.0f * d * d), s_sw2[j * KAN_GRID + g], out);
        }
    }
    return SOFTPLUS(out) * dt;
}

// software barrier among the CBLK parareal blocks (counter pre-zeroed)
__device__ __forceinline__ void grid_barrier(int* bar, int nblk) {
    __syncthreads();
    __threadfence();   // release: flush this block's writes
    if (threadIdx.x == 0) {
        __hip_atomic_fetch_add(bar, 1, __ATOMIC_RELEASE,
                               __HIP_MEMORY_SCOPE_AGENT);
        while (__hip_atomic_load(bar, __ATOMIC_RELAXED,
                                 __HIP_MEMORY_SCOPE_AGENT) < nblk)
            __builtin_amdgcn_s_sleep(1);
    }
    __syncthreads();
    __threadfence();   // acquire: drop stale cached lines
}

// in-block redundant affine scan: all chunk-start states into g_lds
__device__ __forceinline__ void block_affine_scan(
    const float* __restrict__ ja, const float* __restrict__ jb,
    const float* __restrict__ jc, const float* __restrict__ jd,
    const float* __restrict__ cs, const float* __restrict__ ci,
    int K, float S0, float I0,
    float2* g_lds, float (*wm)[6], float (*we)[6])
{
    int tid  = threadIdx.x;
    int lane = tid & 63;
    int wid  = tid >> 6;

    float Fa[SNPT], Fb[SNPT], Fc[SNPT], Fd[SNPT], Fs[SNPT], Fi[SNPT];
    float ma = 1.0f, mb = 0.0f, mc = 0.0f, md = 1.0f, ms = 0.0f, mi = 0.0f;
#pragma unroll
    for (int i = 0; i < SNPT; ++i) {
        int e = tid * SNPT + i;
        if (e < K) {
            Fa[i] = ja[e]; Fb[i] = jb[e]; Fc[i] = jc[e];
            Fd[i] = jd[e]; Fs[i] = cs[e]; Fi[i] = ci[e];
        } else {
            Fa[i] = 1.0f; Fb[i] = 0.0f; Fc[i] = 0.0f;
            Fd[i] = 1.0f; Fs[i] = 0.0f; Fi[i] = 0.0f;
        }
        float na, nb, nc, nd, ns, ni;
        COMPOSE(na,nb,nc,nd,ns,ni, Fa[i],Fb[i],Fc[i],Fd[i],Fs[i],Fi[i],
                                   ma,mb,mc,md,ms,mi);
        ma=na; mb=nb; mc=nc; md=nd; ms=ns; mi=ni;
    }

    for (int off = 1; off < 64; off <<= 1) {
        float pa = __shfl_up(ma, off), pb = __shfl_up(mb, off);
        float pc = __shfl_up(mc, off), pd = __shfl_up(md, off);
        float ps = __shfl_up(ms, off), pi = __shfl_up(mi, off);
        if (lane >= off) {
            float na, nb, nc, nd, ns, ni;
            COMPOSE(na,nb,nc,nd,ns,ni, ma,mb,mc,md,ms,mi, pa,pb,pc,pd,ps,pi);
            ma=na; mb=nb; mc=nc; md=nd; ms=ns; mi=ni;
        }
    }

    if (lane == 63) {
        wm[wid][0]=ma; wm[wid][1]=mb; wm[wid][2]=mc;
        wm[wid][3]=md; wm[wid][4]=ms; wm[wid][5]=mi;
    }
    __syncthreads();

    if (tid == 0) {
        float ra=1.0f, rb=0.0f, rc=0.0f, rd=1.0f, rs=0.0f, ri=0.0f;
        for (int w = 0; w < 4; ++w) {
            we[w][0]=ra; we[w][1]=rb; we[w][2]=rc;
            we[w][3]=rd; we[w][4]=rs; we[w][5]=ri;
            float na, nb, nc, nd, ns, ni;
            COMPOSE(na,nb,nc,nd,ns,ni,
                    wm[w][0],wm[w][1],wm[w][2],wm[w][3],wm[w][4],wm[w][5],
                    ra,rb,rc,rd,rs,ri);
            ra=na; rb=nb; rc=nc; rd=nd; rs=ns; ri=ni;
        }
    }
    __syncthreads();

    float xa = __shfl_up(ma, 1), xb = __shfl_up(mb, 1);
    float xc = __shfl_up(mc, 1), xd = __shfl_up(md, 1);
    float xs = __shfl_up(ms, 1), xi = __shfl_up(mi, 1);
    if (lane == 0) { xa=1.0f; xb=0.0f; xc=0.0f; xd=1.0f; xs=0.0f; xi=0.0f; }
    float Ca, Cb, Cc, Cd, Cs, Ci;
    COMPOSE(Ca,Cb,Cc,Cd,Cs,Ci, xa,xb,xc,xd,xs,xi,
            we[wid][0],we[wid][1],we[wid][2],we[wid][3],we[wid][4],we[wid][5]);

#pragma unroll
    for (int i = 0; i < SNPT; ++i) {
        int e = tid * SNPT + i;
        if (e < K) {
            float gS = fmaf(Ca, S0, fmaf(Cb, I0, Cs));
            float gI = fmaf(Cc, S0, fmaf(Cd, I0, Ci));
            g_lds[e] = make_float2(gS, gI);
        }
        float na, nb, nc, nd, ns, ni;
        COMPOSE(na,nb,nc,nd,ns,ni, Fa[i],Fb[i],Fc[i],Fd[i],Fs[i],Fi[i],
                                   Ca,Cb,Cc,Cd,Cs,Ci);
        Ca=na; Cb=nb; Cc=nc; Cd=nd; Cs=ns; Ci=ni;
    }
    __syncthreads();
}

// ---------------- mega-kernel: betas producers + parareal consumers --------
// Blocks [0, nbeta): compute betas into beta_t[[L][K] layout], arrive, exit.
// Blocks [nbeta, nbeta+CBLK): spin for betas, then 3-phase Newton-parareal
// with 2 internal software barriers (bar[1], bar[2]). bar pre-zeroed by a
// memset node earlier in the stream.
template<int L>
__global__ __launch_bounds__(256, 1) void kan_sir_mega_kernel(
    const float* __restrict__ t,
    const float* __restrict__ I_init,
    const float* __restrict__ gamma_param,
    const float* __restrict__ sw1,
    const float* __restrict__ bw1,
    const float* __restrict__ sw2,
    const float* __restrict__ bw2,
    float* __restrict__ beta_t,   // [L][K]
    float* __restrict__ A,        // 6K floats
    float* __restrict__ B,        // 6K floats
    int* __restrict__ bar,        // 3 ints, pre-zeroed
    float* __restrict__ out,
    int T, int K, int nbeta)
{
    __shared__ float s_sw1[KAN_GRID * KAN_HID];
    __shared__ float s_sw2[KAN_HID * KAN_GRID];
    __shared__ float s_bw1[KAN_HID];
    __shared__ float s_bw2[KAN_HID];
    __shared__ float2 g_lds[PK];
    __shared__ float wm[4][6], we[4][6];

    int bid = blockIdx.x;
    int tid = threadIdx.x;

    if (bid < nbeta) {
        // ---------------- producer: betas ----------------
        for (int i = tid; i < KAN_GRID * KAN_HID; i += blockDim.x) {
            s_sw1[i] = sw1[i];
            s_sw2[i] = sw2[i];
        }
        if (tid < KAN_HID) {
            s_bw1[tid] = bw1[tid];
            s_bw2[tid] = bw2[tid];
        }
        __syncthreads();

        int m = bid * 256 + tid;
        if (m < T) {
            int n = (m % K) * L + m / K;   // time index for [L][K] layout
            float dt = t[1] - t[0];
            beta_t[m] = kan_beta_eval(t[n], s_sw1, s_sw2, s_bw1, s_bw2, dt);
        }
        __syncthreads();
        __threadfence();   // flush betas to device scope
        if (tid == 0)
            __hip_atomic_fetch_add(bar, 1, __ATOMIC_RELEASE,
                                   __HIP_MEMORY_SCOPE_AGENT);
        return;
    }

    // ---------------- consumer: Newton-parareal ----------------
    if (tid == 0) {
        while (__hip_atomic_load(bar, __ATOMIC_RELAXED,
                                 __HIP_MEMORY_SCOPE_AGENT) < nbeta)
            __builtin_amdgcn_s_sleep(1);
    }
    __syncthreads();
    __threadfence();   // acquire: betas now visible

    float dt = t[1] - t[0];
    float gdt = SOFTPLUS(gamma_param[0]) * dt;
    float g1 = 1.0f - gdt;
    float I0 = I_init[0];
    float S0 = 1.0f - I0;

    int k = (bid - nbeta) * 256 + tid;

    // betas for my chunk: load once, reuse in all three phases
    float b[L];
    if (k < K) {
#pragma unroll
        for (int s = 0; s < L; ++s) b[s] = beta_t[s * K + k];
    }

    // ---- Phase A: from uniform start ----
    if (k < K) {
        float S = S0, I = I0;
        float ja = 1.0f, jb = 0.0f, jc = 0.0f, jd = 1.0f;
#pragma unroll
        for (int s = 0; s < L; ++s) { float bdt = b[s]; STEP_J(bdt); }
        A[k]       = ja; A[K + k]   = jb; A[2*K + k] = jc; A[3*K + k] = jd;
        A[4*K + k] = S - fmaf(ja, S0, jb * I0);
        A[5*K + k] = I - fmaf(jc, S0, jd * I0);
    }
    grid_barrier(bar + 1, CBLK);

    // ---- Phase B: scan(setA) -> starts; propagate -> setB ----
    block_affine_scan(A, A + K, A + 2*K, A + 3*K, A + 4*K, A + 5*K,
                      K, S0, I0, g_lds, wm, we);
    if (k < K) {
        float2 g = g_lds[k];
        float S = g.x, I = g.y;
        float ja = 1.0f, jb = 0.0f, jc = 0.0f, jd = 1.0f;
#pragma unroll
        for (int s = 0; s < L; ++s) { float bdt = b[s]; STEP_J(bdt); }
        B[k]       = ja; B[K + k]   = jb; B[2*K + k] = jc; B[3*K + k] = jd;
        B[4*K + k] = S - fmaf(ja, g.x, jb * g.y);
        B[5*K + k] = I - fmaf(jc, g.x, jd * g.y);
    }
    grid_barrier(bar + 2, CBLK);

    // ---- Phase C: scan(setB) -> starts; output ----
    block_affine_scan(B, B + K, B + 2*K, B + 3*K, B + 4*K, B + 5*K,
                      K, S0, I0, g_lds, wm, we);
    if (k < K) {
        float2 g = g_lds[k];
        float S = g.x, I = g.y;
        float4* o4 = (float4*)(out + (size_t)k * L);
#pragma unroll
        for (int i = 0; i < L / 4; ++i) {
            float4 r;
            STEP_O(b[4*i],     r.x);
            STEP_O(b[4*i + 1], r.y);
            STEP_O(b[4*i + 2], r.z);
            STEP_O(b[4*i + 3], r.w);
            o4[i] = r;
        }
    }
}

// ---------------- fallback path (round-1 validated) ------------------------
__global__ __launch_bounds__(256) void kan_betas_kernel(
    const float* __restrict__ t,
    const float* __restrict__ sw1,
    const float* __restrict__ bw1,
    const float* __restrict__ sw2,
    const float* __restrict__ bw2,
    float* __restrict__ beta_dt,
    int T)
{
    __shared__ float s_sw1[KAN_GRID * KAN_HID];
    __shared__ float s_sw2[KAN_HID * KAN_GRID];
    __shared__ float s_bw1[KAN_HID];
    __shared__ float s_bw2[KAN_HID];

    for (int i = threadIdx.x; i < KAN_GRID * KAN_HID; i += blockDim.x) {
        s_sw1[i] = sw1[i];
        s_sw2[i] = sw2[i];
    }
    if (threadIdx.x < KAN_HID) {
        s_bw1[threadIdx.x] = bw1[threadIdx.x];
        s_bw2[threadIdx.x] = bw2[threadIdx.x];
    }
    __syncthreads();

    int m = blockIdx.x * blockDim.x + threadIdx.x;
    if (m >= T) return;
    float dt = t[1] - t[0];
    beta_dt[m] = kan_beta_eval(t[m], s_sw1, s_sw2, s_bw1, s_bw2, dt);
}

__global__ void kan_sir_scan_kernel(
    const float* __restrict__ t,
    const float* __restrict__ I_init,
    const float* __restrict__ gamma_param,
    const float* beta_dt,   // may alias out
    float* out,
    int T)
{
    if (threadIdx.x != 0 || blockIdx.x != 0) return;

    float dt = t[1] - t[0];
    float gdt = SOFTPLUS(gamma_param[0]) * dt;

    float I = I_init[0];
    float S = 1.0f - I;

    const float4* b4 = (const float4*)beta_dt;
    float4* o4 = (float4*)out;
    int nvec = T >> 2;

    const int PF = 8;
    float4 buf[PF];
#pragma unroll
    for (int i = 0; i < PF; ++i)
        buf[i] = (i < nvec) ? b4[i] : float4{0.0f, 0.0f, 0.0f, 0.0f};

    for (int base = 0; base < nvec; base += PF) {
#pragma unroll
        for (int i = 0; i < PF; ++i) {
            int c = base + i;
            if (c >= nvec) break;
            float4 b = buf[i];
            int nxt = c + PF;
            if (nxt < nvec) buf[i] = b4[nxt];

            float4 r;
            STEP_O(b.x, r.x);
            STEP_O(b.y, r.y);
            STEP_O(b.z, r.z);
            STEP_O(b.w, r.w);
            o4[c] = r;
        }
    }
    for (int n = nvec << 2; n < T; ++n) {
        float bdt = beta_dt[n];
        float r;
        STEP_O(bdt, r);
        out[n] = r;
    }
}

extern "C" void kernel_launch(void* const* d_in, const int* in_sizes, int n_in,
                              void* d_out, int out_size, void* d_ws, size_t ws_size,
                              hipStream_t stream) {
    const float* t      = (const float*)d_in[0];
    const float* I_init = (const float*)d_in[1];
    const float* sw1    = (const float*)d_in[2];
    const float* bw1    = (const float*)d_in[3];
    const float* sw2    = (const float*)d_in[4];
    const float* bw2    = (const float*)d_in[5];
    const float* gp     = (const float*)d_in[6];
    int T = in_sizes[0];

    float* outf = (float*)d_out;
    float* ws   = (float*)d_ws;
    int nbeta = (T + 255) / 256;   // 391

    const int K = PK;
    size_t need = ((size_t)T + 12 * K) * sizeof(float) + 3 * sizeof(int);
    bool fast = (T == PK * PL) && (ws_size >= need);

    if (fast) {
        float* beta_t = ws;                 // [L][K]
        float* A = ws + T;                  // setA: 6K
        float* B = A + 6 * K;               // setB: 6K
        int* bar = (int*)(B + 6 * K);       // 3 barrier counters

        hipMemsetAsync(bar, 0, 3 * sizeof(int), stream);
        kan_sir_mega_kernel<PL><<<nbeta + CBLK, 256, 0, stream>>>(
            t, I_init, gp, sw1, bw1, sw2, bw2,
            beta_t, A, B, bar, outf, T, K, nbeta);
    } else {
        float* betab = (ws_size >= (size_t)T * sizeof(float)) ? ws : outf;
        kan_betas_kernel<<<nbeta, 256, 0, stream>>>(t, sw1, bw1, sw2, bw2,
                                                    betab, T);
        kan_sir_scan_kernel<<<1, 64, 0, stream>>>(t, I_init, gp, betab, outf, T);
    }
}

// Round 8
// 38.682 us; speedup vs baseline: 1.9173x; 1.9173x over previous
//
#include <hip/hip_runtime.h>
#include <hip/hip_bf16.h>

#define KAN_GRID 30
#define KAN_HID  16

#define PK   2500    // chunks
#define PL   40      // steps per chunk (PK*PL == T == 100000)
#define SNPT 10      // scan elements per thread (256*10 >= PK)
#define CBLK ((PK + 255) / 256)   // 10 parareal blocks

// Gaussian-ladder constants for grid step D=1/29, width 20:
//   E_{g+1} = E_g * u_g,  u_{g+1} = u_g * LQ
//   E_0 = exp(-20 x^2),  u_0 = exp(40*D*x - 20*D^2)
#define LC1 1.3793103448275863f    // 40/29
#define LC2 0.023781212841854935f  // 20/841
#define LQ  0.953550945f           // exp(-40/841), correctly rounded

// ---------------- step macros (round-1 validated arithmetic) ---------------
#define STEP_O(BDT, DST)                            \
    {                                               \
        float x  = S * I;                           \
        float q  = fmaf(-gdt, I, I);                \
        float Sn = fmaf(-(BDT), x, S);              \
        float In = fmaf((BDT), x, q);               \
        Sn = fminf(fmaxf(Sn, 0.0f), 1.0f);          \
        In = fminf(fmaxf(In, 0.0f), 1.0f);          \
        S = Sn; I = In; (DST) = In;                 \
    }

#define STEP_J(BDT)                                          \
    {                                                        \
        float x  = S * I;                                    \
        float u  = (BDT) * I;                                \
        float v  = (BDT) * S;                                \
        float q  = fmaf(-gdt, I, I);                         \
        float Sn = fmaf(-(BDT), x, S);                       \
        float In = fmaf((BDT), x, q);                        \
        Sn = fminf(fmaxf(Sn, 0.0f), 1.0f);                   \
        In = fminf(fmaxf(In, 0.0f), 1.0f);                   \
        float w  = g1 + v;                                   \
        float a2 = fmaf(-v, jc, fmaf(-u, ja, ja));           \
        float b2 = fmaf(-v, jd, fmaf(-u, jb, jb));           \
        float c2 = fmaf(w, jc, u * ja);                      \
        float d2 = fmaf(w, jd, u * jb);                      \
        S = Sn; I = In; ja = a2; jb = b2; jc = c2; jd = d2;  \
    }

#define SOFTPLUS(X) (fmaxf((X), 0.0f) + log1pf(__expf(-fabsf(X))))

// affine map (a,b,c,d | s,i): x -> [[a,b],[c,d]] x + (s,i). compose = L after E.
#define COMPOSE(ra,rb,rc,rd,rs,ri, La,Lb,Lc,Ld,Ls,Li, Ea,Eb,Ec,Ed,Es,Ei)   \
    {                                                                      \
        ra = fmaf(La, Ea, Lb * Ec);                                        \
        rb = fmaf(La, Eb, Lb * Ed);                                        \
        rc = fmaf(Lc, Ea, Ld * Ec);                                        \
        rd = fmaf(Lc, Eb, Ld * Ed);                                        \
        rs = fmaf(La, Es, fmaf(Lb, Ei, Ls));                               \
        ri = fmaf(Lc, Es, fmaf(Ld, Ei, Li));                               \
    }

// ---------------- Kernel 1: betas via Gaussian ladder -----------------------
// Thread m computes time index n = (m%K)*L + m/K, writes beta_t[m] (coalesced;
// [L][K] layout for the consumer). 2 exps for layer 1, 2 per hidden unit for
// layer 2 (34 total vs 510 naive). Zeroes the fused kernel's barrier counters.
__global__ __launch_bounds__(256, 4) void kan_betas_kernel(
    const float* __restrict__ t,
    const float* __restrict__ sw1,   // [30,16]
    const float* __restrict__ bw1,   // [16,1]
    const float* __restrict__ sw2,   // [480,1]
    const float* __restrict__ bw2,   // [1,16]
    float* __restrict__ beta_dt,
    int* __restrict__ bar,           // 2 ints, may be null
    int T, int K, int L)
{
    __shared__ float s_sw1[KAN_GRID * KAN_HID];
    __shared__ float s_sw2[KAN_HID * KAN_GRID];
    __shared__ float s_bw1[KAN_HID];
    __shared__ float s_bw2[KAN_HID];

    if (bar && blockIdx.x == 0 && threadIdx.x < 2) bar[threadIdx.x] = 0;

    for (int i = threadIdx.x; i < KAN_GRID * KAN_HID; i += blockDim.x) {
        s_sw1[i] = sw1[i];
        s_sw2[i] = sw2[i];
    }
    if (threadIdx.x < KAN_HID) {
        s_bw1[threadIdx.x] = bw1[threadIdx.x];
        s_bw2[threadIdx.x] = bw2[threadIdx.x];
    }
    __syncthreads();

    int m = blockIdx.x * blockDim.x + threadIdx.x;
    if (m >= T) return;

    int n = (m % K) * L + m / K;
    float tv = t[n];
    float dt = t[1] - t[0];

    // Layer 1: h[j] = tv*bw1[j] + sum_g E_g * sw1[g][j], E via ladder
    float h[KAN_HID];
#pragma unroll
    for (int j = 0; j < KAN_HID; ++j) h[j] = tv * s_bw1[j];

    {
        float E = __expf(-20.0f * tv * tv);
        float u = __expf(fmaf(LC1, tv, -LC2));
#pragma unroll
        for (int g = 0; g < KAN_GRID; ++g) {
#pragma unroll
            for (int j = 0; j < KAN_HID; ++j)
                h[j] = fmaf(E, s_sw1[g * KAN_HID + j], h[j]);
            E *= u;
            u *= LQ;
        }
    }

    // Layer 2: out = sum_j h[j]*bw2[j] + sum_j sum_g E_g(h[j]) * sw2[j][g]
    float out = 0.0f;
#pragma unroll
    for (int j = 0; j < KAN_HID; ++j) out = fmaf(h[j], s_bw2[j], out);

#pragma unroll 4
    for (int j = 0; j < KAN_HID; ++j) {
        // clamp ladder start so E0 stays normal; |h|>2 => basis <= 2e-9 ~ 0
        float hv = fminf(fmaxf(h[j], -2.0f), 2.0f);
        float E = __expf(-20.0f * hv * hv);
        float u = __expf(fmaf(LC1, hv, -LC2));
        float acc = 0.0f;
#pragma unroll
        for (int g = 0; g < KAN_GRID; ++g) {
            acc = fmaf(E, s_sw2[j * KAN_GRID + g], acc);
            E *= u;
            u *= LQ;
        }
        out += acc;
    }

    beta_dt[m] = SOFTPLUS(out) * dt;
}

// ---------------- software grid barrier (10 co-resident blocks) ------------
__device__ __forceinline__ void grid_barrier(int* bar, int nblk) {
    __syncthreads();
    __threadfence();   // release
    if (threadIdx.x == 0) {
        __hip_atomic_fetch_add(bar, 1, __ATOMIC_RELEASE,
                               __HIP_MEMORY_SCOPE_AGENT);
        while (__hip_atomic_load(bar, __ATOMIC_RELAXED,
                                 __HIP_MEMORY_SCOPE_AGENT) < nblk)
            __builtin_amdgcn_s_sleep(1);
    }
    __syncthreads();
    __threadfence();   // acquire
}

// ---------------- in-block redundant affine scan ---------------------------
__device__ __forceinline__ void block_affine_scan(
    const float* __restrict__ ja, const float* __restrict__ jb,
    const float* __restrict__ jc, const float* __restrict__ jd,
    const float* __restrict__ cs, const float* __restrict__ ci,
    int K, float S0, float I0,
    float2* g_lds, float (*wm)[6], float (*we)[6])
{
    int tid  = threadIdx.x;
    int lane = tid & 63;
    int wid  = tid >> 6;

    float Fa[SNPT], Fb[SNPT], Fc[SNPT], Fd[SNPT], Fs[SNPT], Fi[SNPT];
    float ma = 1.0f, mb = 0.0f, mc = 0.0f, md = 1.0f, ms = 0.0f, mi = 0.0f;
#pragma unroll
    for (int i = 0; i < SNPT; ++i) {
        int e = tid * SNPT + i;
        if (e < K) {
            Fa[i] = ja[e]; Fb[i] = jb[e]; Fc[i] = jc[e];
            Fd[i] = jd[e]; Fs[i] = cs[e]; Fi[i] = ci[e];
        } else {
            Fa[i] = 1.0f; Fb[i] = 0.0f; Fc[i] = 0.0f;
            Fd[i] = 1.0f; Fs[i] = 0.0f; Fi[i] = 0.0f;
        }
        float na, nb, nc, nd, ns, ni;
        COMPOSE(na,nb,nc,nd,ns,ni, Fa[i],Fb[i],Fc[i],Fd[i],Fs[i],Fi[i],
                                   ma,mb,mc,md,ms,mi);
        ma=na; mb=nb; mc=nc; md=nd; ms=ns; mi=ni;
    }

    for (int off = 1; off < 64; off <<= 1) {
        float pa = __shfl_up(ma, off), pb = __shfl_up(mb, off);
        float pc = __shfl_up(mc, off), pd = __shfl_up(md, off);
        float ps = __shfl_up(ms, off), pi = __shfl_up(mi, off);
        if (lane >= off) {
            float na, nb, nc, nd, ns, ni;
            COMPOSE(na,nb,nc,nd,ns,ni, ma,mb,mc,md,ms,mi, pa,pb,pc,pd,ps,pi);
            ma=na; mb=nb; mc=nc; md=nd; ms=ns; mi=ni;
        }
    }

    if (lane == 63) {
        wm[wid][0]=ma; wm[wid][1]=mb; wm[wid][2]=mc;
        wm[wid][3]=md; wm[wid][4]=ms; wm[wid][5]=mi;
    }
    __syncthreads();

    if (tid == 0) {
        float ra=1.0f, rb=0.0f, rc=0.0f, rd=1.0f, rs=0.0f, ri=0.0f;
        for (int w = 0; w < 4; ++w) {
            we[w][0]=ra; we[w][1]=rb; we[w][2]=rc;
            we[w][3]=rd; we[w][4]=rs; we[w][5]=ri;
            float na, nb, nc, nd, ns, ni;
            COMPOSE(na,nb,nc,nd,ns,ni,
                    wm[w][0],wm[w][1],wm[w][2],wm[w][3],wm[w][4],wm[w][5],
                    ra,rb,rc,rd,rs,ri);
            ra=na; rb=nb; rc=nc; rd=nd; rs=ns; ri=ni;
        }
    }
    __syncthreads();

    float xa = __shfl_up(ma, 1), xb = __shfl_up(mb, 1);
    float xc = __shfl_up(mc, 1), xd = __shfl_up(md, 1);
    float xs = __shfl_up(ms, 1), xi = __shfl_up(mi, 1);
    if (lane == 0) { xa=1.0f; xb=0.0f; xc=0.0f; xd=1.0f; xs=0.0f; xi=0.0f; }
    float Ca, Cb, Cc, Cd, Cs, Ci;
    COMPOSE(Ca,Cb,Cc,Cd,Cs,Ci, xa,xb,xc,xd,xs,xi,
            we[wid][0],we[wid][1],we[wid][2],we[wid][3],we[wid][4],we[wid][5]);

#pragma unroll
    for (int i = 0; i < SNPT; ++i) {
        int e = tid * SNPT + i;
        if (e < K) {
            float gS = fmaf(Ca, S0, fmaf(Cb, I0, Cs));
            float gI = fmaf(Cc, S0, fmaf(Cd, I0, Ci));
            g_lds[e] = make_float2(gS, gI);
        }
        float na, nb, nc, nd, ns, ni;
        COMPOSE(na,nb,nc,nd,ns,ni, Fa[i],Fb[i],Fc[i],Fd[i],Fs[i],Fi[i],
                                   Ca,Cb,Cc,Cd,Cs,Ci);
        Ca=na; Cb=nb; Cc=nc; Cd=nd; Cs=ns; Ci=ni;
    }
    __syncthreads();
}

// ---------------- fused parareal kernel (round-6 validated) ----------------
template<int L>
__global__ __launch_bounds__(256, 1) void sir_fused_kernel(
    const float* __restrict__ t,
    const float* __restrict__ I_init,
    const float* __restrict__ gamma_param,
    const float* __restrict__ beta_t,   // [L][K]
    float* __restrict__ A,              // 6K floats
    float* __restrict__ B,              // 6K floats
    int* __restrict__ bar,              // 2 ints, pre-zeroed
    float* __restrict__ out,
    int K)
{
    __shared__ float2 g_lds[PK];
    __shared__ float wm[4][6], we[4][6];

    float dt = t[1] - t[0];
    float gdt = SOFTPLUS(gamma_param[0]) * dt;
    float g1 = 1.0f - gdt;
    float I0 = I_init[0];
    float S0 = 1.0f - I0;

    int k = blockIdx.x * blockDim.x + threadIdx.x;

    float b[L];
    if (k < K) {
#pragma unroll
        for (int s = 0; s < L; ++s) b[s] = beta_t[s * K + k];
    }

    // ---- Phase A ----
    if (k < K) {
        float S = S0, I = I0;
        float ja = 1.0f, jb = 0.0f, jc = 0.0f, jd = 1.0f;
#pragma unroll
        for (int s = 0; s < L; ++s) { float bdt = b[s]; STEP_J(bdt); }
        A[k]       = ja; A[K + k]   = jb; A[2*K + k] = jc; A[3*K + k] = jd;
        A[4*K + k] = S - fmaf(ja, S0, jb * I0);
        A[5*K + k] = I - fmaf(jc, S0, jd * I0);
    }
    grid_barrier(bar, gridDim.x);

    // ---- Phase B ----
    block_affine_scan(A, A + K, A + 2*K, A + 3*K, A + 4*K, A + 5*K,
                      K, S0, I0, g_lds, wm, we);
    if (k < K) {
        float2 g = g_lds[k];
        float S = g.x, I = g.y;
        float ja = 1.0f, jb = 0.0f, jc = 0.0f, jd = 1.0f;
#pragma unroll
        for (int s = 0; s < L; ++s) { float bdt = b[s]; STEP_J(bdt); }
        B[k]       = ja; B[K + k]   = jb; B[2*K + k] = jc; B[3*K + k] = jd;
        B[4*K + k] = S - fmaf(ja, g.x, jb * g.y);
        B[5*K + k] = I - fmaf(jc, g.x, jd * g.y);
    }
    grid_barrier(bar + 1, gridDim.x);

    // ---- Phase C ----
    block_affine_scan(B, B + K, B + 2*K, B + 3*K, B + 4*K, B + 5*K,
                      K, S0, I0, g_lds, wm, we);
    if (k < K) {
        float2 g = g_lds[k];
        float S = g.x, I = g.y;
        float4* o4 = (float4*)(out + (size_t)k * L);
#pragma unroll
        for (int i = 0; i < L / 4; ++i) {
            float4 r;
            STEP_O(b[4*i],     r.x);
            STEP_O(b[4*i + 1], r.y);
            STEP_O(b[4*i + 2], r.z);
            STEP_O(b[4*i + 3], r.w);
            o4[i] = r;
        }
    }
}

// ---------------- fallback: serial scan (round-1 validated) ----------------
__global__ void kan_sir_scan_kernel(
    const float* __restrict__ t,
    const float* __restrict__ I_init,
    const float* __restrict__ gamma_param,
    const float* beta_dt,   // may alias out
    float* out,
    int T)
{
    if (threadIdx.x != 0 || blockIdx.x != 0) return;

    float dt = t[1] - t[0];
    float gdt = SOFTPLUS(gamma_param[0]) * dt;

    float I = I_init[0];
    float S = 1.0f - I;

    const float4* b4 = (const float4*)beta_dt;
    float4* o4 = (float4*)out;
    int nvec = T >> 2;

    const int PF = 8;
    float4 buf[PF];
#pragma unroll
    for (int i = 0; i < PF; ++i)
        buf[i] = (i < nvec) ? b4[i] : float4{0.0f, 0.0f, 0.0f, 0.0f};

    for (int base = 0; base < nvec; base += PF) {
#pragma unroll
        for (int i = 0; i < PF; ++i) {
            int c = base + i;
            if (c >= nvec) break;
            float4 b = buf[i];
            int nxt = c + PF;
            if (nxt < nvec) buf[i] = b4[nxt];

            float4 r;
            STEP_O(b.x, r.x);
            STEP_O(b.y, r.y);
            STEP_O(b.z, r.z);
            STEP_O(b.w, r.w);
            o4[c] = r;
        }
    }
    for (int n = nvec << 2; n < T; ++n) {
        float bdt = beta_dt[n];
        float r;
        STEP_O(bdt, r);
        out[n] = r;
    }
}

extern "C" void kernel_launch(void* const* d_in, const int* in_sizes, int n_in,
                              void* d_out, int out_size, void* d_ws, size_t ws_size,
                              hipStream_t stream) {
    const float* t      = (const float*)d_in[0];
    const float* I_init = (const float*)d_in[1];
    const float* sw1    = (const float*)d_in[2];
    const float* bw1    = (const float*)d_in[3];
    const float* sw2    = (const float*)d_in[4];
    const float* bw2    = (const float*)d_in[5];
    const float* gp     = (const float*)d_in[6];
    int T = in_sizes[0];

    float* outf = (float*)d_out;
    float* ws   = (float*)d_ws;
    int bblocks = (T + 255) / 256;

    const int K = PK;
    size_t need = ((size_t)T + 12 * K) * sizeof(float) + 2 * sizeof(int);
    bool fast = (T == PK * PL) && (ws_size >= need);

    if (fast) {
        float* beta_t = ws;                 // [L][K]
        float* A = ws + T;                  // setA: 6K
        float* B = A + 6 * K;               // setB: 6K
        int* bar = (int*)(B + 6 * K);       // 2 barrier counters

        kan_betas_kernel<<<bblocks, 256, 0, stream>>>(t, sw1, bw1, sw2, bw2,
                                                      beta_t, bar, T, K, PL);
        sir_fused_kernel<PL><<<CBLK, 256, 0, stream>>>(
            t, I_init, gp, beta_t, A, B, bar, outf, K);
    } else {
        float* betab = (ws_size >= (size_t)T * sizeof(float)) ? ws : outf;
        kan_betas_kernel<<<bblocks, 256, 0, stream>>>(t, sw1, bw1, sw2, bw2,
                                                      betab, nullptr, T, T, 1);
        kan_sir_scan_kernel<<<1, 64, 0, stream>>>(t, I_init, gp, betab, outf, T);
    }
}